// Round 2
// baseline (1216.269 us; speedup 1.0000x reference)
//
#include <hip/hip_runtime.h>
#include <hip/hip_bf16.h>

#define HW 4096
#define CCH 240

// ---------------- per-channel sum / sumsq ----------------
__global__ __launch_bounds__(256) void chan_stats(const float* __restrict__ in,
                                                  float* __restrict__ cs,
                                                  float* __restrict__ cq) {
  int c = blockIdx.x;
  const float4* p = reinterpret_cast<const float4*>(in + (size_t)c * HW);
  float s = 0.f, q = 0.f;
  for (int i = threadIdx.x; i < HW / 4; i += 256) {
    float4 v = p[i];
    s += v.x + v.y + v.z + v.w;
    q += v.x * v.x + v.y * v.y + v.z * v.z + v.w * v.w;
  }
  for (int off = 32; off > 0; off >>= 1) {
    s += __shfl_down(s, off);
    q += __shfl_down(q, off);
  }
  __shared__ float ls[4], lq[4];
  int wid = threadIdx.x >> 6, lane = threadIdx.x & 63;
  if (lane == 0) { ls[wid] = s; lq[wid] = q; }
  __syncthreads();
  if (threadIdx.x == 0) {
    cs[c] = ls[0] + ls[1] + ls[2] + ls[3];
    cq[c] = lq[0] + lq[1] + lq[2] + lq[3];
  }
}

__device__ __forceinline__ float silu_f(float u) { return u / (1.f + __expf(-u)); }
__device__ __forceinline__ float sigm_f(float u) { return 1.f / (1.f + __expf(-u)); }

// in-block 4-group finalize from per-channel partials
__device__ __forceinline__ void group_stats(const float* cs, const float* cq, int cpg,
                                            float* sm, float* sr) {
  if (threadIdx.x < 4) {
    int g = threadIdx.x;
    float s = 0.f, q = 0.f;
    for (int c = 0; c < cpg; c++) { s += cs[g * cpg + c]; q += cq[g * cpg + c]; }
    float n = (float)cpg * (float)HW;
    float m = s / n;
    float v = q / n - m * m;
    sm[g] = m;
    sr[g] = rsqrtf(v + 1e-5f);
  }
  __syncthreads();
}

// ---------------- apply GN to x: h1 = silu(gn1(x)), xn = gn_sa(x) ----------------
__global__ __launch_bounds__(256) void apply_x(const float* __restrict__ x,
                                               const float* __restrict__ cs, const float* __restrict__ cq,
                                               const float* __restrict__ g1, const float* __restrict__ b1,
                                               const float* __restrict__ gs, const float* __restrict__ bs,
                                               float* __restrict__ h1, float* __restrict__ xn) {
  __shared__ float sm[4], sr[4];
  group_stats(cs, cq, 60, sm, sr);
  int idx = blockIdx.x * 256 + threadIdx.x;   // over 240*1024 float4
  if (idx >= CCH * (HW / 4)) return;
  int c = idx >> 10;
  int g = c / 60;
  float m = sm[g], r = sr[g];
  float a1 = r * g1[c], o1 = b1[c] - m * a1;
  float a2 = r * gs[c], o2 = bs[c] - m * a2;
  float4 v = reinterpret_cast<const float4*>(x)[idx];
  float4 h, w;
  h.x = silu_f(v.x * a1 + o1); h.y = silu_f(v.y * a1 + o1);
  h.z = silu_f(v.z * a1 + o1); h.w = silu_f(v.w * a1 + o1);
  w.x = v.x * a2 + o2; w.y = v.y * a2 + o2;
  w.z = v.z * a2 + o2; w.w = v.w * a2 + o2;
  reinterpret_cast<float4*>(h1)[idx] = h;
  reinterpret_cast<float4*>(xn)[idx] = w;
}

// ---------------- generic apply GN + silu ----------------
__global__ __launch_bounds__(256) void apply_gn_silu(const float* __restrict__ in,
                                                     const float* __restrict__ cs, const float* __restrict__ cq,
                                                     const float* __restrict__ gamma, const float* __restrict__ beta,
                                                     float* __restrict__ out, int nchan, int cpg) {
  __shared__ float sm[4], sr[4];
  group_stats(cs, cq, cpg, sm, sr);
  int idx = blockIdx.x * 256 + threadIdx.x;
  if (idx >= nchan * (HW / 4)) return;
  int c = idx >> 10;
  int g = c / cpg;
  float m = sm[g], r = sr[g];
  float a = r * gamma[c], o = beta[c] - m * a;
  float4 v = reinterpret_cast<const float4*>(in)[idx];
  float4 h;
  h.x = silu_f(v.x * a + o); h.y = silu_f(v.y * a + o);
  h.z = silu_f(v.z * a + o); h.w = silu_f(v.w * a + o);
  reinterpret_cast<float4*>(out)[idx] = h;
}

// ---------------- direct 3x3 conv, pad=1 ----------------
// tile: 16 co x (2 rows x 64 x); thread: 2 co x 4 px
template <int FUSE>   // 0: out = acc+bias ; 1: out = acc+bias+xres (final)
__global__ __launch_bounds__(256) void conv3(const float* __restrict__ in, const float* __restrict__ w,
                                             const float* __restrict__ bias, float* __restrict__ out,
                                             int Cin, int Cout, const float* __restrict__ xres) {
  const int pxt = blockIdx.x;          // 0..31
  const int co0 = blockIdx.y * 16;
  const int r0 = pxt * 2;
  const int tid = threadIdx.x;
  const int pxg = tid & 31;
  const int x0 = (pxg & 15) * 4;
  const int rloc = pxg >> 4;           // 0..1
  const int col0 = (tid >> 5) * 2;     // local co (0,2,..,14)

  __shared__ float sIn[16][4][68];     // padded to 68: rows 16B-aligned (272B stride)
  __shared__ float sW[16][9][16];      // [ci][tap][co_local]

  float acc[2][4];
#pragma unroll
  for (int a = 0; a < 2; a++)
#pragma unroll
    for (int b = 0; b < 4; b++) acc[a][b] = 0.f;

  for (int ci0 = 0; ci0 < Cin; ci0 += 16) {
    __syncthreads();
    for (int e = tid; e < 16 * 4 * 66; e += 256) {
      int ci = e / (4 * 66);
      int rem = e % (4 * 66);
      int rr = rem / 66;
      int xx = rem % 66;
      int gr = r0 - 1 + rr;
      int gx = xx - 1;
      float v = 0.f;
      if ((ci0 + ci) < Cin && gr >= 0 && gr < 64 && gx >= 0 && gx < 64)
        v = in[(size_t)(ci0 + ci) * HW + gr * 64 + gx];
      sIn[ci][rr][xx] = v;
    }
    for (int e = tid; e < 16 * 9 * 16; e += 256) {
      int ci = e / (9 * 16);
      int rem = e % (9 * 16);
      int tap = rem / 16;
      int col = rem % 16;
      int co = co0 + col;
      float v = 0.f;
      if ((ci0 + ci) < Cin && co < Cout) v = w[(size_t)co * Cin * 9 + (ci0 + ci) * 9 + tap];
      sW[ci][tap][col] = v;
    }
    __syncthreads();
#pragma unroll 4
    for (int ci = 0; ci < 16; ci++) {
      float win[3][6];
#pragma unroll
      for (int r = 0; r < 3; r++) {
        float4 a4 = *reinterpret_cast<const float4*>(&sIn[ci][rloc + r][x0]);
        float2 a2 = *reinterpret_cast<const float2*>(&sIn[ci][rloc + r][x0 + 4]);
        win[r][0] = a4.x; win[r][1] = a4.y; win[r][2] = a4.z;
        win[r][3] = a4.w; win[r][4] = a2.x; win[r][5] = a2.y;
      }
#pragma unroll
      for (int ky = 0; ky < 3; ky++)
#pragma unroll
        for (int kx = 0; kx < 3; kx++) {
          float2 w2 = *reinterpret_cast<const float2*>(&sW[ci][ky * 3 + kx][col0]);
#pragma unroll
          for (int j = 0; j < 4; j++) {
            float iv = win[ky][j + kx];
            acc[0][j] = fmaf(w2.x, iv, acc[0][j]);
            acc[1][j] = fmaf(w2.y, iv, acc[1][j]);
          }
        }
    }
  }
  int row = r0 + rloc;
#pragma unroll
  for (int a = 0; a < 2; a++) {
    int co = co0 + col0 + a;
    if (co < Cout) {
      float bv = bias[co];
#pragma unroll
      for (int j = 0; j < 4; j++) {
        int p = row * 64 + x0 + j;
        float v = acc[a][j] + bv;
        if (FUSE == 1) v += xres[(size_t)co * HW + p];
        out[(size_t)co * HW + p] = v;
      }
    }
  }
}

// ---------------- SE block (tiny, 1 block) ----------------
__global__ __launch_bounds__(256) void se_kernel(const float* __restrict__ csh,
                                                 const float* __restrict__ w1, const float* __restrict__ b1,
                                                 const float* __restrict__ w2, const float* __restrict__ b2,
                                                 float* __restrict__ y2g) {
  __shared__ float hm[240];
  __shared__ float y1[8];
  int tid = threadIdx.x;
  if (tid < 240) hm[tid] = csh[tid] * (1.f / 4096.f);
  __syncthreads();
  if (tid < 8) {
    float a = b1[tid];
    for (int c = 0; c < 240; c++) a = fmaf(w1[tid * 240 + c], hm[c], a);
    y1[tid] = silu_f(a);
  }
  __syncthreads();
  if (tid < 240) {
    float a = b2[tid];
#pragma unroll
    for (int s = 0; s < 8; s++) a = fmaf(w2[tid * 8 + s], y1[s], a);
    y2g[tid] = sigm_f(a);
  }
}

// ---------------- GEMM: out[M][4096] = A[M][K] * B[K][4096] ----------------
// tile 16m x 256n, thread 4m x 4n
template <int FUSE>  // 0: +bias(if non-null); 1: proj fusion -> t = acc+bias+2x+h2*y2*x
__global__ __launch_bounds__(256) void gemm16(const float* __restrict__ A, const float* __restrict__ B,
                                              const float* __restrict__ bias, float* __restrict__ out,
                                              int M, int K,
                                              const float* __restrict__ x, const float* __restrict__ h2,
                                              const float* __restrict__ y2) {
  const int n0 = blockIdx.x * 256;
  const int m0 = blockIdx.y * 16;
  const int tid = threadIdx.x;
  const int tn = (tid & 63) * 4;
  const int tm = (tid >> 6) * 4;
  __shared__ float sA[16][16];
  __shared__ float sB[16][256];
  float acc[4][4] = {};
  for (int k0 = 0; k0 < K; k0 += 16) {
    __syncthreads();
    {
      int ml = tid & 15, kl = tid >> 4;
      float v = 0.f;
      if (m0 + ml < M && k0 + kl < K) v = A[(size_t)(m0 + ml) * K + k0 + kl];
      sA[kl][ml] = v;
    }
    for (int e = tid; e < 16 * 64; e += 256) {
      int kl = e >> 6, nn4 = e & 63;
      float4 v = make_float4(0.f, 0.f, 0.f, 0.f);
      if (k0 + kl < K) v = *reinterpret_cast<const float4*>(&B[(size_t)(k0 + kl) * HW + n0 + nn4 * 4]);
      reinterpret_cast<float4*>(&sB[kl][0])[nn4] = v;
    }
    __syncthreads();
#pragma unroll
    for (int k = 0; k < 16; k++) {
      float4 a4 = *reinterpret_cast<const float4*>(&sA[k][tm]);
      float4 b4 = *reinterpret_cast<const float4*>(&sB[k][tn]);
      acc[0][0] = fmaf(a4.x, b4.x, acc[0][0]); acc[0][1] = fmaf(a4.x, b4.y, acc[0][1]);
      acc[0][2] = fmaf(a4.x, b4.z, acc[0][2]); acc[0][3] = fmaf(a4.x, b4.w, acc[0][3]);
      acc[1][0] = fmaf(a4.y, b4.x, acc[1][0]); acc[1][1] = fmaf(a4.y, b4.y, acc[1][1]);
      acc[1][2] = fmaf(a4.y, b4.z, acc[1][2]); acc[1][3] = fmaf(a4.y, b4.w, acc[1][3]);
      acc[2][0] = fmaf(a4.z, b4.x, acc[2][0]); acc[2][1] = fmaf(a4.z, b4.y, acc[2][1]);
      acc[2][2] = fmaf(a4.z, b4.z, acc[2][2]); acc[2][3] = fmaf(a4.z, b4.w, acc[2][3]);
      acc[3][0] = fmaf(a4.w, b4.x, acc[3][0]); acc[3][1] = fmaf(a4.w, b4.y, acc[3][1]);
      acc[3][2] = fmaf(a4.w, b4.z, acc[3][2]); acc[3][3] = fmaf(a4.w, b4.w, acc[3][3]);
    }
  }
#pragma unroll
  for (int i = 0; i < 4; i++) {
    int m = m0 + tm + i;
    if (m >= M) continue;
    size_t base = (size_t)m * HW + n0 + tn;
    float bv = bias ? bias[m] : 0.f;
    float4 o;
    o.x = acc[i][0] + bv; o.y = acc[i][1] + bv; o.z = acc[i][2] + bv; o.w = acc[i][3] + bv;
    if (FUSE == 1) {
      float yv = y2[m];
      float4 xv = *reinterpret_cast<const float4*>(&x[base]);
      float4 hv = *reinterpret_cast<const float4*>(&h2[base]);
      o.x += 2.f * xv.x + hv.x * yv * xv.x;
      o.y += 2.f * xv.y + hv.y * yv * xv.y;
      o.z += 2.f * xv.z + hv.z * yv * xv.z;
      o.w += 2.f * xv.w + hv.w * yv * xv.w;
    }
    *reinterpret_cast<float4*>(&out[base]) = o;
  }
}

// ---------------- flash attention, split-KV partials ----------------
// grid: (16 qtiles, 8 heads, 4 splits); 256 threads, 1 query/thread
__global__ __launch_bounds__(256, 2) void flash_part(const float* __restrict__ qkv,
                                                     float* __restrict__ pacc,
                                                     float* __restrict__ pm, float* __restrict__ pl) {
  const int h = blockIdx.y, sp = blockIdx.z;
  const int t = blockIdx.x * 256 + threadIdx.x;
  const float* qb = qkv + (size_t)(h * 90) * HW;
  const float* kb = qb + 30 * HW;
  const float* vb = qb + 60 * HW;
  const float s2 = 0.18257418583505536f;  // 30^-0.5
  float q[30];
#pragma unroll
  for (int d = 0; d < 30; d++) q[d] = qb[(size_t)d * HW + t] * s2;
  float acc[30];
#pragma unroll
  for (int d = 0; d < 30; d++) acc[d] = 0.f;
  float mr = -1e30f, lr = 0.f;
  __shared__ float sK[30][64], sV[30][64];
  const int s_begin = sp * 1024;
  for (int s0 = s_begin; s0 < s_begin + 1024; s0 += 64) {
    __syncthreads();
    for (int e = threadIdx.x; e < 30 * 64; e += 256) {
      int d = e >> 6, cc = e & 63;
      sK[d][cc] = kb[(size_t)d * HW + s0 + cc];
      sV[d][cc] = vb[(size_t)d * HW + s0 + cc];
    }
    __syncthreads();
    float sc[64];
#pragma unroll
    for (int j4 = 0; j4 < 16; j4++) {
      float ax = 0.f, ay = 0.f, az = 0.f, aw = 0.f;
#pragma unroll
      for (int d = 0; d < 30; d++) {
        float4 k4 = *reinterpret_cast<const float4*>(&sK[d][j4 * 4]);
        float qd = q[d];
        ax = fmaf(qd, k4.x, ax); ay = fmaf(qd, k4.y, ay);
        az = fmaf(qd, k4.z, az); aw = fmaf(qd, k4.w, aw);
      }
      sc[j4 * 4 + 0] = ax; sc[j4 * 4 + 1] = ay; sc[j4 * 4 + 2] = az; sc[j4 * 4 + 3] = aw;
    }
    float mt = sc[0];
#pragma unroll
    for (int j = 1; j < 64; j++) mt = fmaxf(mt, sc[j]);
    float mnew = fmaxf(mr, mt);
    float alpha = __expf(mr - mnew);
    mr = mnew;
    float ls = 0.f;
#pragma unroll
    for (int j = 0; j < 64; j++) { sc[j] = __expf(sc[j] - mr); ls += sc[j]; }
    lr = lr * alpha + ls;
#pragma unroll
    for (int d = 0; d < 30; d++) {
      float a = 0.f;
#pragma unroll
      for (int j4 = 0; j4 < 16; j4++) {
        float4 v4 = *reinterpret_cast<const float4*>(&sV[d][j4 * 4]);
        a = fmaf(sc[j4 * 4 + 0], v4.x, a); a = fmaf(sc[j4 * 4 + 1], v4.y, a);
        a = fmaf(sc[j4 * 4 + 2], v4.z, a); a = fmaf(sc[j4 * 4 + 3], v4.w, a);
      }
      acc[d] = acc[d] * alpha + a;
    }
  }
  const int sh = sp * 8 + h;
#pragma unroll
  for (int d = 0; d < 30; d++) pacc[((size_t)sh * 30 + d) * HW + t] = acc[d];
  pm[(size_t)sh * HW + t] = mr;
  pl[(size_t)sh * HW + t] = lr;
}

// ---------------- flash merge ----------------
__global__ __launch_bounds__(256) void flash_merge(const float* __restrict__ pacc,
                                                   const float* __restrict__ pm, const float* __restrict__ pl,
                                                   float* __restrict__ hs) {
  int idx = blockIdx.x * 256 + threadIdx.x;  // 240*4096
  if (idx >= CCH * HW) return;
  int c = idx >> 12;
  int t = idx & 4095;
  int hh = c / 30;
  int d = c % 30;
  float pmv[4];
  float mx = -1e30f;
#pragma unroll
  for (int sp = 0; sp < 4; sp++) {
    pmv[sp] = pm[(size_t)(sp * 8 + hh) * HW + t];
    mx = fmaxf(mx, pmv[sp]);
  }
  float den = 0.f, num = 0.f;
#pragma unroll
  for (int sp = 0; sp < 4; sp++) {
    float wgt = __expf(pmv[sp] - mx);
    den = fmaf(pl[(size_t)(sp * 8 + hh) * HW + t], wgt, den);
    num = fmaf(pacc[((size_t)(sp * 8 + hh) * 30 + d) * HW + t], wgt, num);
  }
  hs[idx] = num / den;
}

// ---------------- launch ----------------
extern "C" void kernel_launch(void* const* d_in, const int* in_sizes, int n_in,
                              void* d_out, int out_size, void* d_ws, size_t ws_size,
                              hipStream_t stream) {
  const float* x        = (const float*)d_in[0];
  const float* ca_gn1_g = (const float*)d_in[1];
  const float* ca_gn1_b = (const float*)d_in[2];
  const float* ca_c1_w  = (const float*)d_in[3];
  const float* ca_c1_b  = (const float*)d_in[4];
  const float* ca_gn2_g = (const float*)d_in[5];
  const float* ca_gn2_b = (const float*)d_in[6];
  const float* ca_c2_w  = (const float*)d_in[7];
  const float* ca_c2_b  = (const float*)d_in[8];
  const float* se1_w    = (const float*)d_in[9];
  const float* se1_b    = (const float*)d_in[10];
  const float* se2_w    = (const float*)d_in[11];
  const float* se2_b    = (const float*)d_in[12];
  const float* sa_gn_g  = (const float*)d_in[13];
  const float* sa_gn_b  = (const float*)d_in[14];
  const float* qkv_w    = (const float*)d_in[15];
  const float* proj_w   = (const float*)d_in[16];
  const float* proj_b   = (const float*)d_in[17];
  const float* res_gn_g = (const float*)d_in[18];
  const float* res_gn_b = (const float*)d_in[19];
  const float* res_w    = (const float*)d_in[20];
  const float* res_b    = (const float*)d_in[21];
  float* out = (float*)d_out;
  float* ws = (float*)d_ws;

  // workspace layout (floats)
  float* h1   = ws + 0;         // 983040   (reused as hs)
  float* xn   = ws + 983040;    // 983040   (reused as t)
  float* c1   = ws + 1966080;   // 245760   (region reused as pm/pl)
  float* c1n  = ws + 2211840;   // 245760
  float* h2   = ws + 2457600;   // 983040
  float* qkvb = ws + 3440640;   // 2949120  (reused as tn)
  float* pacc = ws + 6389760;   // 4*240*4096 = 3932160
  float* S    = ws + 10321920;  // small arrays
  float* csx = S + 0,   *cqx = S + 240;
  float* cs2 = S + 512, *cq2 = S + 576;
  float* csh = S + 704, *cqh = S + 944;
  float* y2g = S + 1184;
  float* csr = S + 1424, *cqr = S + 1664;
  float* pm = ws + 1966080;         // 4*8*4096 = 131072
  float* pl = ws + 1966080 + 131072;
  float* hs = h1;
  float* t  = xn;
  float* tn = qkvb;

  // 1-2: GN stats on x, apply gn1(silu) and sa_gn (finalize fused)
  chan_stats<<<240, 256, 0, stream>>>(x, csx, cqx);
  apply_x<<<960, 256, 0, stream>>>(x, csx, cqx, ca_gn1_g, ca_gn1_b, sa_gn_g, sa_gn_b, h1, xn);
  // 3: conv1 240->60
  conv3<0><<<dim3(32, 4), 256, 0, stream>>>(h1, ca_c1_w, ca_c1_b, c1, 240, 60, nullptr);
  // 4-5: gn2 + silu
  chan_stats<<<60, 256, 0, stream>>>(c1, cs2, cq2);
  apply_gn_silu<<<240, 256, 0, stream>>>(c1, cs2, cq2, ca_gn2_g, ca_gn2_b, c1n, 60, 15);
  // 6: conv2 60->240
  conv3<0><<<dim3(32, 15), 256, 0, stream>>>(c1n, ca_c2_w, ca_c2_b, h2, 60, 240, nullptr);
  // 7-8: SE
  chan_stats<<<240, 256, 0, stream>>>(h2, csh, cqh);
  se_kernel<<<1, 256, 0, stream>>>(csh, se1_w, se1_b, se2_w, se2_b, y2g);
  // 9: qkv gemm 720x4096x240
  gemm16<0><<<dim3(16, 45), 256, 0, stream>>>(qkv_w, xn, nullptr, qkvb, 720, 240,
                                              nullptr, nullptr, nullptr);
  // 10-11: flash attention
  flash_part<<<dim3(16, 8, 4), 256, 0, stream>>>(qkvb, pacc, pm, pl);
  flash_merge<<<3840, 256, 0, stream>>>(pacc, pm, pl, hs);
  // 12: proj gemm + fuse: t = proj(hs)+pb + 2x + h2*y2*x
  gemm16<1><<<dim3(16, 15), 256, 0, stream>>>(proj_w, hs, proj_b, t, 240, 240, x, h2, y2g);
  // 13-14: res GN + silu
  chan_stats<<<240, 256, 0, stream>>>(t, csr, cqr);
  apply_gn_silu<<<960, 256, 0, stream>>>(t, csr, cqr, res_gn_g, res_gn_b, tn, 240, 60);
  // 15: final conv 240->240 fused +bias+x -> d_out
  conv3<1><<<dim3(32, 15), 256, 0, stream>>>(tn, res_w, res_b, out, 240, 240, x);
}

// Round 7
// 745.622 us; speedup vs baseline: 1.6312x; 1.6312x over previous
//
#include <hip/hip_runtime.h>
#include <hip/hip_bf16.h>

#define HW 4096
#define CCH 240

typedef __bf16 bf16x8 __attribute__((ext_vector_type(8)));
typedef float f32x4 __attribute__((ext_vector_type(4)));

// ---------------- per-channel sum / sumsq ----------------
__global__ __launch_bounds__(256) void chan_stats(const float* __restrict__ in,
                                                  float* __restrict__ cs,
                                                  float* __restrict__ cq) {
  int c = blockIdx.x;
  const float4* p = reinterpret_cast<const float4*>(in + (size_t)c * HW);
  float s = 0.f, q = 0.f;
  for (int i = threadIdx.x; i < HW / 4; i += 256) {
    float4 v = p[i];
    s += v.x + v.y + v.z + v.w;
    q += v.x * v.x + v.y * v.y + v.z * v.z + v.w * v.w;
  }
  for (int off = 32; off > 0; off >>= 1) {
    s += __shfl_down(s, off);
    q += __shfl_down(q, off);
  }
  __shared__ float ls[4], lq[4];
  int wid = threadIdx.x >> 6, lane = threadIdx.x & 63;
  if (lane == 0) { ls[wid] = s; lq[wid] = q; }
  __syncthreads();
  if (threadIdx.x == 0) {
    cs[c] = ls[0] + ls[1] + ls[2] + ls[3];
    cq[c] = lq[0] + lq[1] + lq[2] + lq[3];
  }
}

__device__ __forceinline__ float silu_f(float u) { return u / (1.f + __expf(-u)); }
__device__ __forceinline__ float sigm_f(float u) { return 1.f / (1.f + __expf(-u)); }

// in-block 4-group finalize from per-channel partials
__device__ __forceinline__ void group_stats(const float* cs, const float* cq, int cpg,
                                            float* sm, float* sr) {
  if (threadIdx.x < 4) {
    int g = threadIdx.x;
    float s = 0.f, q = 0.f;
    for (int c = 0; c < cpg; c++) { s += cs[g * cpg + c]; q += cq[g * cpg + c]; }
    float n = (float)cpg * (float)HW;
    float m = s / n;
    float v = q / n - m * m;
    sm[g] = m;
    sr[g] = rsqrtf(v + 1e-5f);
  }
  __syncthreads();
}

// ---------------- apply GN to x: h1 = silu(gn1(x)), xn = gn_sa(x) ----------------
__global__ __launch_bounds__(256) void apply_x(const float* __restrict__ x,
                                               const float* __restrict__ cs, const float* __restrict__ cq,
                                               const float* __restrict__ g1, const float* __restrict__ b1,
                                               const float* __restrict__ gs, const float* __restrict__ bs,
                                               float* __restrict__ h1, float* __restrict__ xn) {
  __shared__ float sm[4], sr[4];
  group_stats(cs, cq, 60, sm, sr);
  int idx = blockIdx.x * 256 + threadIdx.x;   // over 240*1024 float4
  if (idx >= CCH * (HW / 4)) return;
  int c = idx >> 10;
  int g = c / 60;
  float m = sm[g], r = sr[g];
  float a1 = r * g1[c], o1 = b1[c] - m * a1;
  float a2 = r * gs[c], o2 = bs[c] - m * a2;
  float4 v = reinterpret_cast<const float4*>(x)[idx];
  float4 h, w;
  h.x = silu_f(v.x * a1 + o1); h.y = silu_f(v.y * a1 + o1);
  h.z = silu_f(v.z * a1 + o1); h.w = silu_f(v.w * a1 + o1);
  w.x = v.x * a2 + o2; w.y = v.y * a2 + o2;
  w.z = v.z * a2 + o2; w.w = v.w * a2 + o2;
  reinterpret_cast<float4*>(h1)[idx] = h;
  reinterpret_cast<float4*>(xn)[idx] = w;
}

// ---------------- generic apply GN + silu ----------------
__global__ __launch_bounds__(256) void apply_gn_silu(const float* __restrict__ in,
                                                     const float* __restrict__ cs, const float* __restrict__ cq,
                                                     const float* __restrict__ gamma, const float* __restrict__ beta,
                                                     float* __restrict__ out, int nchan, int cpg) {
  __shared__ float sm[4], sr[4];
  group_stats(cs, cq, cpg, sm, sr);
  int idx = blockIdx.x * 256 + threadIdx.x;
  if (idx >= nchan * (HW / 4)) return;
  int c = idx >> 10;
  int g = c / cpg;
  float m = sm[g], r = sr[g];
  float a = r * gamma[c], o = beta[c] - m * a;
  float4 v = reinterpret_cast<const float4*>(in)[idx];
  float4 h;
  h.x = silu_f(v.x * a + o); h.y = silu_f(v.y * a + o);
  h.z = silu_f(v.z * a + o); h.w = silu_f(v.w * a + o);
  reinterpret_cast<float4*>(out)[idx] = h;
}

// ---------------- direct 3x3 conv, pad=1 ----------------
template <int FUSE>   // 0: out = acc+bias ; 1: out = acc+bias+xres (final)
__global__ __launch_bounds__(256) void conv3(const float* __restrict__ in, const float* __restrict__ w,
                                             const float* __restrict__ bias, float* __restrict__ out,
                                             int Cin, int Cout, const float* __restrict__ xres) {
  const int pxt = blockIdx.x;          // 0..31
  const int co0 = blockIdx.y * 16;
  const int r0 = pxt * 2;
  const int tid = threadIdx.x;
  const int pxg = tid & 31;
  const int x0 = (pxg & 15) * 4;
  const int rloc = pxg >> 4;           // 0..1
  const int col0 = (tid >> 5) * 2;     // local co (0,2,..,14)

  __shared__ float sIn[16][4][68];
  __shared__ float sW[16][9][16];

  float acc[2][4];
#pragma unroll
  for (int a = 0; a < 2; a++)
#pragma unroll
    for (int b = 0; b < 4; b++) acc[a][b] = 0.f;

  for (int ci0 = 0; ci0 < Cin; ci0 += 16) {
    __syncthreads();
    for (int e = tid; e < 16 * 4 * 66; e += 256) {
      int ci = e / (4 * 66);
      int rem = e % (4 * 66);
      int rr = rem / 66;
      int xx = rem % 66;
      int gr = r0 - 1 + rr;
      int gx = xx - 1;
      float v = 0.f;
      if ((ci0 + ci) < Cin && gr >= 0 && gr < 64 && gx >= 0 && gx < 64)
        v = in[(size_t)(ci0 + ci) * HW + gr * 64 + gx];
      sIn[ci][rr][xx] = v;
    }
    for (int e = tid; e < 16 * 9 * 16; e += 256) {
      int ci = e / (9 * 16);
      int rem = e % (9 * 16);
      int tap = rem / 16;
      int col = rem % 16;
      int co = co0 + col;
      float v = 0.f;
      if ((ci0 + ci) < Cin && co < Cout) v = w[(size_t)co * Cin * 9 + (ci0 + ci) * 9 + tap];
      sW[ci][tap][col] = v;
    }
    __syncthreads();
#pragma unroll 4
    for (int ci = 0; ci < 16; ci++) {
      float win[3][6];
#pragma unroll
      for (int r = 0; r < 3; r++) {
        float4 a4 = *reinterpret_cast<const float4*>(&sIn[ci][rloc + r][x0]);
        float2 a2 = *reinterpret_cast<const float2*>(&sIn[ci][rloc + r][x0 + 4]);
        win[r][0] = a4.x; win[r][1] = a4.y; win[r][2] = a4.z;
        win[r][3] = a4.w; win[r][4] = a2.x; win[r][5] = a2.y;
      }
#pragma unroll
      for (int ky = 0; ky < 3; ky++)
#pragma unroll
        for (int kx = 0; kx < 3; kx++) {
          float2 w2 = *reinterpret_cast<const float2*>(&sW[ci][ky * 3 + kx][col0]);
#pragma unroll
          for (int j = 0; j < 4; j++) {
            float iv = win[ky][j + kx];
            acc[0][j] = fmaf(w2.x, iv, acc[0][j]);
            acc[1][j] = fmaf(w2.y, iv, acc[1][j]);
          }
        }
    }
  }
  int row = r0 + rloc;
#pragma unroll
  for (int a = 0; a < 2; a++) {
    int co = co0 + col0 + a;
    if (co < Cout) {
      float bv = bias[co];
#pragma unroll
      for (int j = 0; j < 4; j++) {
        int p = row * 64 + x0 + j;
        float v = acc[a][j] + bv;
        if (FUSE == 1) v += xres[(size_t)co * HW + p];
        out[(size_t)co * HW + p] = v;
      }
    }
  }
}

// ---------------- SE block (tiny, 1 block) ----------------
__global__ __launch_bounds__(256) void se_kernel(const float* __restrict__ csh,
                                                 const float* __restrict__ w1, const float* __restrict__ b1,
                                                 const float* __restrict__ w2, const float* __restrict__ b2,
                                                 float* __restrict__ y2g) {
  __shared__ float hm[240];
  __shared__ float y1[8];
  int tid = threadIdx.x;
  if (tid < 240) hm[tid] = csh[tid] * (1.f / 4096.f);
  __syncthreads();
  if (tid < 8) {
    float a = b1[tid];
    for (int c = 0; c < 240; c++) a = fmaf(w1[tid * 240 + c], hm[c], a);
    y1[tid] = silu_f(a);
  }
  __syncthreads();
  if (tid < 240) {
    float a = b2[tid];
#pragma unroll
    for (int s = 0; s < 8; s++) a = fmaf(w2[tid * 8 + s], y1[s], a);
    y2g[tid] = sigm_f(a);
  }
}

// ---------------- GEMM: out[M][4096] = A[M][K] * B[K][4096] ----------------
template <int FUSE>  // 0: +bias(if non-null); 1: proj fusion -> t = acc+bias+2x+h2*y2*x
__global__ __launch_bounds__(256) void gemm16(const float* __restrict__ A, const float* __restrict__ B,
                                              const float* __restrict__ bias, float* __restrict__ out,
                                              int M, int K,
                                              const float* __restrict__ x, const float* __restrict__ h2,
                                              const float* __restrict__ y2) {
  const int n0 = blockIdx.x * 256;
  const int m0 = blockIdx.y * 16;
  const int tid = threadIdx.x;
  const int tn = (tid & 63) * 4;
  const int tm = (tid >> 6) * 4;
  __shared__ float sA[16][16];
  __shared__ float sB[16][256];
  float acc[4][4] = {};
  for (int k0 = 0; k0 < K; k0 += 16) {
    __syncthreads();
    {
      int ml = tid & 15, kl = tid >> 4;
      float v = 0.f;
      if (m0 + ml < M && k0 + kl < K) v = A[(size_t)(m0 + ml) * K + k0 + kl];
      sA[kl][ml] = v;
    }
    for (int e = tid; e < 16 * 64; e += 256) {
      int kl = e >> 6, nn4 = e & 63;
      float4 v = make_float4(0.f, 0.f, 0.f, 0.f);
      if (k0 + kl < K) v = *reinterpret_cast<const float4*>(&B[(size_t)(k0 + kl) * HW + n0 + nn4 * 4]);
      reinterpret_cast<float4*>(&sB[kl][0])[nn4] = v;
    }
    __syncthreads();
#pragma unroll
    for (int k = 0; k < 16; k++) {
      float4 a4 = *reinterpret_cast<const float4*>(&sA[k][tm]);
      float4 b4 = *reinterpret_cast<const float4*>(&sB[k][tn]);
      acc[0][0] = fmaf(a4.x, b4.x, acc[0][0]); acc[0][1] = fmaf(a4.x, b4.y, acc[0][1]);
      acc[0][2] = fmaf(a4.x, b4.z, acc[0][2]); acc[0][3] = fmaf(a4.x, b4.w, acc[0][3]);
      acc[1][0] = fmaf(a4.y, b4.x, acc[1][0]); acc[1][1] = fmaf(a4.y, b4.y, acc[1][1]);
      acc[1][2] = fmaf(a4.y, b4.z, acc[1][2]); acc[1][3] = fmaf(a4.y, b4.w, acc[1][3]);
      acc[2][0] = fmaf(a4.z, b4.x, acc[2][0]); acc[2][1] = fmaf(a4.z, b4.y, acc[2][1]);
      acc[2][2] = fmaf(a4.z, b4.z, acc[2][2]); acc[2][3] = fmaf(a4.z, b4.w, acc[2][3]);
      acc[3][0] = fmaf(a4.w, b4.x, acc[3][0]); acc[3][1] = fmaf(a4.w, b4.y, acc[3][1]);
      acc[3][2] = fmaf(a4.w, b4.z, acc[3][2]); acc[3][3] = fmaf(a4.w, b4.w, acc[3][3]);
    }
  }
#pragma unroll
  for (int i = 0; i < 4; i++) {
    int m = m0 + tm + i;
    if (m >= M) continue;
    size_t base = (size_t)m * HW + n0 + tn;
    float bv = bias ? bias[m] : 0.f;
    float4 o;
    o.x = acc[i][0] + bv; o.y = acc[i][1] + bv; o.z = acc[i][2] + bv; o.w = acc[i][3] + bv;
    if (FUSE == 1) {
      float yv = y2[m];
      float4 xv = *reinterpret_cast<const float4*>(&x[base]);
      float4 hv = *reinterpret_cast<const float4*>(&h2[base]);
      o.x += 2.f * xv.x + hv.x * yv * xv.x;
      o.y += 2.f * xv.y + hv.y * yv * xv.y;
      o.z += 2.f * xv.z + hv.z * yv * xv.z;
      o.w += 2.f * xv.w + hv.w * yv * xv.w;
    }
    *reinterpret_cast<float4*>(&out[base]) = o;
  }
}

// ---------------- prep: qkv f32 [720][4096] -> qT/kT bf16 [8][4096][32], vP bf16 [8][32][4096]
// q pre-scaled by 30^-0.5 * log2(e) (softmax runs in exp2 domain)
__global__ __launch_bounds__(256) void prep_qkv(const float* __restrict__ qkvb,
                                                __hip_bfloat16* __restrict__ qT,
                                                __hip_bfloat16* __restrict__ kT,
                                                __hip_bfloat16* __restrict__ vP) {
  const int h = blockIdx.y, t0 = blockIdx.x * 256;
  const int tid = threadIdx.x;
  __shared__ float sT[30][258];
  const float qscale = 0.26340180f;  // 30^-1/2 * log2(e)
#pragma unroll
  for (int sect = 0; sect < 2; sect++) {
    __syncthreads();
    for (int e = tid; e < 30 * 256; e += 256) {
      int d = e >> 8, t = e & 255;
      sT[d][t] = qkvb[(size_t)(h * 90 + sect * 30 + d) * HW + t0 + t];
    }
    __syncthreads();
    float sc = (sect == 0) ? qscale : 1.f;
    __hip_bfloat16* dst = (sect == 0 ? qT : kT) + (size_t)h * HW * 32;
    for (int e = tid; e < 256 * 16; e += 256) {
      int t = e >> 4, d2 = e & 15;
      float lo = 0.f, hi = 0.f;
      if (d2 < 15) { lo = sT[2 * d2][t] * sc; hi = sT[2 * d2 + 1][t] * sc; }
      unsigned u;
      asm("v_cvt_pk_bf16_f32 %0, %1, %2" : "=v"(u) : "v"(lo), "v"(hi));
      reinterpret_cast<unsigned*>(dst)[(size_t)(t0 + t) * 16 + d2] = u;
    }
  }
  // V: bf16, rows 30,31 zero-padded
  for (int e = tid; e < 32 * 128; e += 256) {
    int d = e >> 7, t2 = e & 127;
    float lo = 0.f, hi = 0.f;
    if (d < 30) {
      const float* src = qkvb + (size_t)(h * 90 + 60 + d) * HW + t0;
      lo = src[2 * t2];
      hi = src[2 * t2 + 1];
    }
    unsigned u;
    asm("v_cvt_pk_bf16_f32 %0, %1, %2" : "=v"(u) : "v"(lo), "v"(hi));
    reinterpret_cast<unsigned*>(vP)[((size_t)(h * 32 + d) * HW + t0) / 2 + t2] = u;
  }
}

// ---------------- MFMA flash attention (split-KV=2 partials) ----------------
// grid (64 qtiles, 8 heads, 2 splits), 256 threads = 4 waves, 16 q/wave.
// No __syncthreads in KV loop: P round-trips a per-wave-private LDS slice.
__global__ __launch_bounds__(256) void flash_mfma(const __hip_bfloat16* __restrict__ qT,
                                                  const __hip_bfloat16* __restrict__ kT,
                                                  const __hip_bfloat16* __restrict__ vP,
                                                  float* __restrict__ pacc,
                                                  float* __restrict__ pm, float* __restrict__ pl) {
  const int h = blockIdx.y, sp = blockIdx.z;
  const int wid = threadIdx.x >> 6, lane = threadIdx.x & 63;
  const int l15 = lane & 15, lg = lane >> 4;
  const int qw = blockIdx.x * 64 + wid * 16;  // wave's 16-q base
  const __hip_bfloat16* qTh = qT + (size_t)h * HW * 32;
  const __hip_bfloat16* kTh = kT + (size_t)h * HW * 32;
  const __hip_bfloat16* vPh = vP + (size_t)h * 32 * HW;

  // Q A-frag resident all loop: row q = qw+l15, d = lg*8+j
  bf16x8 qa = *reinterpret_cast<const bf16x8*>(qTh + (size_t)(qw + l15) * 32 + lg * 8);

  f32x4 o0 = {0.f, 0.f, 0.f, 0.f}, o1 = {0.f, 0.f, 0.f, 0.f};
  float m[4] = {-1e30f, -1e30f, -1e30f, -1e30f};
  float lsum[4] = {0.f, 0.f, 0.f, 0.f};

  __shared__ ushort plds_all[4][64][20];  // per-wave P^T [k][q], stride 20 (bank-spread)
  ushort (*plds)[20] = plds_all[wid];

  const int srcl = (l15 >> 2) << 4;  // lane holding row-stats for q-col l15
  const int rr = l15 & 3;

  const int k_begin = sp * 2048;
  for (int k0 = k_begin; k0 < k_begin + 2048; k0 += 64) {
    // ---- S = Q·K^T (4 MFMAs; C: row=q=4*lg+r, col=k=16t+l15) ----
    f32x4 s[4];
#pragma unroll
    for (int t = 0; t < 4; t++) {
      bf16x8 kb = *reinterpret_cast<const bf16x8*>(kTh + (size_t)(k0 + t * 16 + l15) * 32 + lg * 8);
      f32x4 z = {0.f, 0.f, 0.f, 0.f};
      s[t] = __builtin_amdgcn_mfma_f32_16x16x32_bf16(qa, kb, z, 0, 0, 0);
    }
    // ---- online softmax (exp2 domain), per q-row r (row = 4*lg + r) ----
    float a[4];
#pragma unroll
    for (int r = 0; r < 4; r++) {
      float v = fmaxf(fmaxf(s[0][r], s[1][r]), fmaxf(s[2][r], s[3][r]));
      v = fmaxf(v, __shfl_xor(v, 1));
      v = fmaxf(v, __shfl_xor(v, 2));
      v = fmaxf(v, __shfl_xor(v, 4));
      v = fmaxf(v, __shfl_xor(v, 8));
      float mn = fmaxf(m[r], v);
      a[r] = exp2f(m[r] - mn);
      m[r] = mn;
      float rs = 0.f;
#pragma unroll
      for (int t = 0; t < 4; t++) {
        s[t][r] = exp2f(s[t][r] - mn);
        rs += s[t][r];
      }
      rs += __shfl_xor(rs, 1);
      rs += __shfl_xor(rs, 2);
      rs += __shfl_xor(rs, 4);
      rs += __shfl_xor(rs, 8);
      lsum[r] = lsum[r] * a[r] + rs;
    }
    // ---- rescale O^T (cols q=l15) by alpha of that q-row ----
    float a0 = __shfl(a[0], srcl), a1 = __shfl(a[1], srcl);
    float a2 = __shfl(a[2], srcl), a3 = __shfl(a[3], srcl);
    float aq = rr == 0 ? a0 : (rr == 1 ? a1 : (rr == 2 ? a2 : a3));
    o0 *= aq;
    o1 *= aq;
    // ---- P -> bf16 -> per-wave LDS as P^T[k][q] ----
#pragma unroll
    for (int t = 0; t < 4; t++) {
      unsigned u01, u23;
      asm("v_cvt_pk_bf16_f32 %0, %1, %2" : "=v"(u01) : "v"(s[t][0]), "v"(s[t][1]));
      asm("v_cvt_pk_bf16_f32 %0, %1, %2" : "=v"(u23) : "v"(s[t][2]), "v"(s[t][3]));
      *reinterpret_cast<uint2*>(&plds[t * 16 + l15][4 * lg]) = make_uint2(u01, u23);
    }
    // ---- PV: O^T += V^T · P^T (2 k-steps x 2 d-tiles) ----
#pragma unroll
    for (int s2 = 0; s2 < 2; s2++) {
      union { ushort u[8]; bf16x8 v; } pb;
#pragma unroll
      for (int j = 0; j < 8; j++) pb.u[j] = plds[s2 * 32 + lg * 8 + j][l15];
      bf16x8 va0 = *reinterpret_cast<const bf16x8*>(vPh + (size_t)l15 * HW + k0 + s2 * 32 + lg * 8);
      bf16x8 va1 = *reinterpret_cast<const bf16x8*>(vPh + (size_t)(16 + l15) * HW + k0 + s2 * 32 + lg * 8);
      o0 = __builtin_amdgcn_mfma_f32_16x16x32_bf16(va0, pb.v, o0, 0, 0, 0);
      o1 = __builtin_amdgcn_mfma_f32_16x16x32_bf16(va1, pb.v, o1, 0, 0, 0);
    }
  }
  // ---- write partials (unnormalized) ----
  const int sh = sp * 8 + h;
  if (l15 == 0) {
#pragma unroll
    for (int r = 0; r < 4; r++) {
      pm[(size_t)sh * HW + qw + 4 * lg + r] = m[r];
      pl[(size_t)sh * HW + qw + 4 * lg + r] = lsum[r];
    }
  }
  float* pbase = pacc + (size_t)sh * 30 * HW;
#pragma unroll
  for (int r = 0; r < 4; r++) {
    int d = 4 * lg + r;
    if (d < 30) pbase[(size_t)d * HW + qw + l15] = o0[r];
    if (d + 16 < 30) pbase[(size_t)(d + 16) * HW + qw + l15] = o1[r];
  }
}

// ---------------- flash merge (exp2 domain, 2 splits) ----------------
__global__ __launch_bounds__(256) void flash_merge(const float* __restrict__ pacc,
                                                   const float* __restrict__ pm, const float* __restrict__ pl,
                                                   float* __restrict__ hs) {
  int idx = blockIdx.x * 256 + threadIdx.x;  // 240*4096
  if (idx >= CCH * HW) return;
  int c = idx >> 12;
  int t = idx & 4095;
  int hh = c / 30;
  int d = c % 30;
  float pmv[2];
  float mx = -1e30f;
#pragma unroll
  for (int sp = 0; sp < 2; sp++) {
    pmv[sp] = pm[(size_t)(sp * 8 + hh) * HW + t];
    mx = fmaxf(mx, pmv[sp]);
  }
  float den = 0.f, num = 0.f;
#pragma unroll
  for (int sp = 0; sp < 2; sp++) {
    float wgt = exp2f(pmv[sp] - mx);
    den = fmaf(pl[(size_t)(sp * 8 + hh) * HW + t], wgt, den);
    num = fmaf(pacc[((size_t)(sp * 8 + hh) * 30 + d) * HW + t], wgt, num);
  }
  hs[idx] = num / den;
}

// ---------------- launch ----------------
extern "C" void kernel_launch(void* const* d_in, const int* in_sizes, int n_in,
                              void* d_out, int out_size, void* d_ws, size_t ws_size,
                              hipStream_t stream) {
  const float* x        = (const float*)d_in[0];
  const float* ca_gn1_g = (const float*)d_in[1];
  const float* ca_gn1_b = (const float*)d_in[2];
  const float* ca_c1_w  = (const float*)d_in[3];
  const float* ca_c1_b  = (const float*)d_in[4];
  const float* ca_gn2_g = (const float*)d_in[5];
  const float* ca_gn2_b = (const float*)d_in[6];
  const float* ca_c2_w  = (const float*)d_in[7];
  const float* ca_c2_b  = (const float*)d_in[8];
  const float* se1_w    = (const float*)d_in[9];
  const float* se1_b    = (const float*)d_in[10];
  const float* se2_w    = (const float*)d_in[11];
  const float* se2_b    = (const float*)d_in[12];
  const float* sa_gn_g  = (const float*)d_in[13];
  const float* sa_gn_b  = (const float*)d_in[14];
  const float* qkv_w    = (const float*)d_in[15];
  const float* proj_w   = (const float*)d_in[16];
  const float* proj_b   = (const float*)d_in[17];
  const float* res_gn_g = (const float*)d_in[18];
  const float* res_gn_b = (const float*)d_in[19];
  const float* res_w    = (const float*)d_in[20];
  const float* res_b    = (const float*)d_in[21];
  float* out = (float*)d_out;
  float* ws = (float*)d_ws;

  // workspace layout (floats); high-water 9.93M floats = 39.7 MB
  // (< 41.3 MB proven to fit in round 2)
  float* h1   = ws + 0;         // 983040   (reused as hs)
  float* xn   = ws + 983040;    // 983040   (reused as t)
  float* c1   = ws + 1966080;   // 245760   (dead after conv2 inputs; reused as pm/pl)
  float* c1n  = ws + 2211840;   // 245760
  float* h2   = ws + 2457600;   // 983040
  float* qkvb = ws + 3440640;   // 2949120  (reused as tn)
  float* pacc = ws + 6389760;   // 2*240*4096 = 1966080
  __hip_bfloat16* qTb = (__hip_bfloat16*)(ws + 8355840);  // 8*4096*32 bf16 = 524288 fl
  __hip_bfloat16* kTb = (__hip_bfloat16*)(ws + 8880128);
  __hip_bfloat16* vPb = (__hip_bfloat16*)(ws + 9404416);
  float* S    = ws + 9928704;   // small arrays
  float* csx = S + 0,   *cqx = S + 240;
  float* cs2 = S + 512, *cq2 = S + 576;
  float* csh = S + 704, *cqh = S + 944;
  float* y2g = S + 1184;
  float* csr = S + 1424, *cqr = S + 1664;
  float* pm = ws + 1966080;           // 2*8*4096 = 65536
  float* pl = ws + 1966080 + 65536;   // ends 2097152 < c1n start
  float* hs = h1;
  float* t  = xn;
  float* tn = qkvb;

  chan_stats<<<240, 256, 0, stream>>>(x, csx, cqx);
  apply_x<<<960, 256, 0, stream>>>(x, csx, cqx, ca_gn1_g, ca_gn1_b, sa_gn_g, sa_gn_b, h1, xn);
  conv3<0><<<dim3(32, 4), 256, 0, stream>>>(h1, ca_c1_w, ca_c1_b, c1, 240, 60, nullptr);
  chan_stats<<<60, 256, 0, stream>>>(c1, cs2, cq2);
  apply_gn_silu<<<240, 256, 0, stream>>>(c1, cs2, cq2, ca_gn2_g, ca_gn2_b, c1n, 60, 15);
  conv3<0><<<dim3(32, 15), 256, 0, stream>>>(c1n, ca_c2_w, ca_c2_b, h2, 60, 240, nullptr);
  chan_stats<<<240, 256, 0, stream>>>(h2, csh, cqh);
  se_kernel<<<1, 256, 0, stream>>>(csh, se1_w, se1_b, se2_w, se2_b, y2g);
  gemm16<0><<<dim3(16, 45), 256, 0, stream>>>(qkv_w, xn, nullptr, qkvb, 720, 240,
                                              nullptr, nullptr, nullptr);
  prep_qkv<<<dim3(16, 8), 256, 0, stream>>>(qkvb, qTb, kTb, vPb);
  flash_mfma<<<dim3(64, 8, 2), 256, 0, stream>>>(qTb, kTb, vPb, pacc, pm, pl);
  flash_merge<<<3840, 256, 0, stream>>>(pacc, pm, pl, hs);
  gemm16<1><<<dim3(16, 15), 256, 0, stream>>>(proj_w, hs, proj_b, t, 240, 240, x, h2, y2g);
  chan_stats<<<240, 256, 0, stream>>>(t, csr, cqr);
  apply_gn_silu<<<960, 256, 0, stream>>>(t, csr, cqr, res_gn_g, res_gn_b, tn, 240, 60);
  conv3<1><<<dim3(32, 15), 256, 0, stream>>>(tn, res_w, res_b, out, 240, 240, x);
}

// Round 11
// 431.742 us; speedup vs baseline: 2.8171x; 1.7270x over previous
//
#include <hip/hip_runtime.h>
#include <hip/hip_bf16.h>

#define HW 4096
#define CCH 240

typedef __bf16 bf16x8 __attribute__((ext_vector_type(8)));
typedef float f32x4 __attribute__((ext_vector_type(4)));

// ---------------- per-channel sum / sumsq ----------------
__global__ __launch_bounds__(256) void chan_stats(const float* __restrict__ in,
                                                  float* __restrict__ cs,
                                                  float* __restrict__ cq) {
  int c = blockIdx.x;
  const float4* p = reinterpret_cast<const float4*>(in + (size_t)c * HW);
  float s = 0.f, q = 0.f;
  for (int i = threadIdx.x; i < HW / 4; i += 256) {
    float4 v = p[i];
    s += v.x + v.y + v.z + v.w;
    q += v.x * v.x + v.y * v.y + v.z * v.z + v.w * v.w;
  }
  for (int off = 32; off > 0; off >>= 1) {
    s += __shfl_down(s, off);
    q += __shfl_down(q, off);
  }
  __shared__ float ls[4], lq[4];
  int wid = threadIdx.x >> 6, lane = threadIdx.x & 63;
  if (lane == 0) { ls[wid] = s; lq[wid] = q; }
  __syncthreads();
  if (threadIdx.x == 0) {
    cs[c] = ls[0] + ls[1] + ls[2] + ls[3];
    cq[c] = lq[0] + lq[1] + lq[2] + lq[3];
  }
}

__device__ __forceinline__ float silu_f(float u) { return u / (1.f + __expf(-u)); }
__device__ __forceinline__ float sigm_f(float u) { return 1.f / (1.f + __expf(-u)); }

// in-block 4-group finalize from per-channel partials
__device__ __forceinline__ void group_stats(const float* cs, const float* cq, int cpg,
                                            float* sm, float* sr) {
  if (threadIdx.x < 4) {
    int g = threadIdx.x;
    float s = 0.f, q = 0.f;
    for (int c = 0; c < cpg; c++) { s += cs[g * cpg + c]; q += cq[g * cpg + c]; }
    float n = (float)cpg * (float)HW;
    float m = s / n;
    float v = q / n - m * m;
    sm[g] = m;
    sr[g] = rsqrtf(v + 1e-5f);
  }
  __syncthreads();
}

// ---------------- apply GN to x: h1 = silu(gn1(x)), xn = gn_sa(x) ----------------
__global__ __launch_bounds__(256) void apply_x(const float* __restrict__ x,
                                               const float* __restrict__ cs, const float* __restrict__ cq,
                                               const float* __restrict__ g1, const float* __restrict__ b1,
                                               const float* __restrict__ gs, const float* __restrict__ bs,
                                               float* __restrict__ h1, float* __restrict__ xn) {
  __shared__ float sm[4], sr[4];
  group_stats(cs, cq, 60, sm, sr);
  int idx = blockIdx.x * 256 + threadIdx.x;   // over 240*1024 float4
  if (idx >= CCH * (HW / 4)) return;
  int c = idx >> 10;
  int g = c / 60;
  float m = sm[g], r = sr[g];
  float a1 = r * g1[c], o1 = b1[c] - m * a1;
  float a2 = r * gs[c], o2 = bs[c] - m * a2;
  float4 v = reinterpret_cast<const float4*>(x)[idx];
  float4 h, w;
  h.x = silu_f(v.x * a1 + o1); h.y = silu_f(v.y * a1 + o1);
  h.z = silu_f(v.z * a1 + o1); h.w = silu_f(v.w * a1 + o1);
  w.x = v.x * a2 + o2; w.y = v.y * a2 + o2;
  w.z = v.z * a2 + o2; w.w = v.w * a2 + o2;
  reinterpret_cast<float4*>(h1)[idx] = h;
  reinterpret_cast<float4*>(xn)[idx] = w;
}

// ---------------- generic apply GN + silu ----------------
__global__ __launch_bounds__(256) void apply_gn_silu(const float* __restrict__ in,
                                                     const float* __restrict__ cs, const float* __restrict__ cq,
                                                     const float* __restrict__ gamma, const float* __restrict__ beta,
                                                     float* __restrict__ out, int nchan, int cpg) {
  __shared__ float sm[4], sr[4];
  group_stats(cs, cq, cpg, sm, sr);
  int idx = blockIdx.x * 256 + threadIdx.x;
  if (idx >= nchan * (HW / 4)) return;
  int c = idx >> 10;
  int g = c / cpg;
  float m = sm[g], r = sr[g];
  float a = r * gamma[c], o = beta[c] - m * a;
  float4 v = reinterpret_cast<const float4*>(in)[idx];
  float4 h;
  h.x = silu_f(v.x * a + o); h.y = silu_f(v.y * a + o);
  h.z = silu_f(v.z * a + o); h.w = silu_f(v.w * a + o);
  reinterpret_cast<float4*>(out)[idx] = h;
}

// ---------------- transpose f32 [C][4096] -> bf16 [4097][CIP] (row 4096 = zeros) ----------------
template <int CIP>
__global__ __launch_bounds__(256) void tp_bf16(const float* __restrict__ in,
                                               __hip_bfloat16* __restrict__ outT, int C) {
  if (blockIdx.x == 64) {  // zero pad row
    if (blockIdx.y == 0 && threadIdx.x < CIP / 2)
      reinterpret_cast<unsigned*>(outT + (size_t)4096 * CIP)[threadIdx.x] = 0u;
    return;
  }
  const int px0 = blockIdx.x * 64, c0 = blockIdx.y * 64;
  __shared__ float sT[64][67];
  const int tid = threadIdx.x;
#pragma unroll
  for (int k = 0; k < 16; k++) {
    int e = tid + k * 256;
    int cc = e >> 6, pp = e & 63;
    float v = (c0 + cc < C) ? in[(size_t)(c0 + cc) * HW + px0 + pp] : 0.f;
    sT[cc][pp] = v;
  }
  __syncthreads();
#pragma unroll
  for (int k = 0; k < 4; k++) {
    int e = tid + k * 256;
    int pp = e >> 4, cl = e & 15;
    float f0 = sT[cl * 4 + 0][pp], f1 = sT[cl * 4 + 1][pp];
    float f2 = sT[cl * 4 + 2][pp], f3 = sT[cl * 4 + 3][pp];
    unsigned u0, u1;
    asm("v_cvt_pk_bf16_f32 %0, %1, %2" : "=v"(u0) : "v"(f0), "v"(f1));
    asm("v_cvt_pk_bf16_f32 %0, %1, %2" : "=v"(u1) : "v"(f2), "v"(f3));
    reinterpret_cast<uint2*>(outT + (size_t)(px0 + pp) * CIP + c0)[cl] = make_uint2(u0, u1);
  }
}

// ---------------- weight repack: f32 [Cout][Cin][3][3] -> bf16 [9][COP][CIP] ----------------
__global__ __launch_bounds__(256) void repack_w(const float* __restrict__ w,
                                                __hip_bfloat16* __restrict__ wB,
                                                int Cout, int Cin, int COP, int CIP) {
  int d2 = blockIdx.x * 256 + threadIdx.x;  // bf16-pair index
  if (d2 >= 9 * COP * CIP / 2) return;
  int ci = (d2 * 2) % CIP;
  int t2 = (d2 * 2) / CIP;
  int co = t2 % COP;
  int tap = t2 / COP;
  float f0 = 0.f, f1 = 0.f;
  if (co < Cout && ci < Cin)     f0 = w[((size_t)co * Cin + ci) * 9 + tap];
  if (co < Cout && ci + 1 < Cin) f1 = w[((size_t)co * Cin + ci + 1) * 9 + tap];
  unsigned u;
  asm("v_cvt_pk_bf16_f32 %0, %1, %2" : "=v"(u) : "v"(f0), "v"(f1));
  reinterpret_cast<unsigned*>(wB)[d2] = u;
}

// ---------------- MFMA implicit-GEMM 3x3 conv, pad=1 ----------------
// out^T[px][co] = sum_tap sum_ci inT[px'][ci] * wB[tap][co][ci]
// grid (64, COP/32); 4 waves; wave = 16 px x 32 co. No LDS, no syncthreads.
template <int CIP, int FUSE>
__global__ __launch_bounds__(256) void conv_mfma(const __hip_bfloat16* __restrict__ inT,
                                                 const __hip_bfloat16* __restrict__ wB,
                                                 const float* __restrict__ bias,
                                                 float* __restrict__ out, int Cout, int COP,
                                                 const float* __restrict__ xres) {
  const int wid = threadIdx.x >> 6, lane = threadIdx.x & 63;
  const int l15 = lane & 15, lg = lane >> 4;
  const int px0 = (blockIdx.x * 4 + wid) * 16;
  const int co0 = blockIdx.y * 32;
  const int px = px0 + l15;
  const int r = px >> 6, c = px & 63;
  int rowIdx[9];
#pragma unroll
  for (int dy = -1; dy <= 1; dy++)
#pragma unroll
    for (int dx = -1; dx <= 1; dx++) {
      int rr2 = r + dy, cc2 = c + dx;
      rowIdx[(dy + 1) * 3 + dx + 1] =
          (rr2 >= 0 && rr2 < 64 && cc2 >= 0 && cc2 < 64) ? rr2 * 64 + cc2 : 4096;
    }
  f32x4 acc0 = {0.f, 0.f, 0.f, 0.f}, acc1 = {0.f, 0.f, 0.f, 0.f};
#pragma unroll
  for (int tap = 0; tap < 9; tap++) {
    const __hip_bfloat16* arow = inT + (size_t)rowIdx[tap] * CIP + lg * 8;
    const __hip_bfloat16* brow = wB + ((size_t)tap * COP + co0 + l15) * CIP + lg * 8;
#pragma unroll
    for (int ck = 0; ck < CIP / 32; ck++) {
      bf16x8 av = *reinterpret_cast<const bf16x8*>(arow + ck * 32);
      bf16x8 b0 = *reinterpret_cast<const bf16x8*>(brow + ck * 32);
      bf16x8 b1 = *reinterpret_cast<const bf16x8*>(brow + 16 * CIP + ck * 32);
      acc0 = __builtin_amdgcn_mfma_f32_16x16x32_bf16(av, b0, acc0, 0, 0, 0);
      acc1 = __builtin_amdgcn_mfma_f32_16x16x32_bf16(av, b1, acc1, 0, 0, 0);
    }
  }
  const int co_a = co0 + l15, co_b = co0 + 16 + l15;
  float ba = (co_a < Cout) ? bias[co_a] : 0.f;
  float bb = (co_b < Cout) ? bias[co_b] : 0.f;
#pragma unroll
  for (int rr = 0; rr < 4; rr++) {
    int opx = px0 + 4 * lg + rr;
    if (co_a < Cout) {
      float v = acc0[rr] + ba;
      if (FUSE) v += xres[(size_t)co_a * HW + opx];
      out[(size_t)co_a * HW + opx] = v;
    }
    if (co_b < Cout) {
      float v = acc1[rr] + bb;
      if (FUSE) v += xres[(size_t)co_b * HW + opx];
      out[(size_t)co_b * HW + opx] = v;
    }
  }
}

// ---------------- SE block (tiny, 1 block) ----------------
__global__ __launch_bounds__(256) void se_kernel(const float* __restrict__ csh,
                                                 const float* __restrict__ w1, const float* __restrict__ b1,
                                                 const float* __restrict__ w2, const float* __restrict__ b2,
                                                 float* __restrict__ y2g) {
  __shared__ float hm[240];
  __shared__ float y1[8];
  int tid = threadIdx.x;
  if (tid < 240) hm[tid] = csh[tid] * (1.f / 4096.f);
  __syncthreads();
  if (tid < 8) {
    float a = b1[tid];
    for (int c = 0; c < 240; c++) a = fmaf(w1[tid * 240 + c], hm[c], a);
    y1[tid] = silu_f(a);
  }
  __syncthreads();
  if (tid < 240) {
    float a = b2[tid];
#pragma unroll
    for (int s = 0; s < 8; s++) a = fmaf(w2[tid * 8 + s], y1[s], a);
    y2g[tid] = sigm_f(a);
  }
}

// ---------------- GEMM: out[M][4096] = A[M][K] * B[K][4096] ----------------
template <int FUSE>  // 0: +bias(if non-null); 1: proj fusion -> t = acc+bias+2x+h2*y2*x
__global__ __launch_bounds__(256) void gemm16(const float* __restrict__ A, const float* __restrict__ B,
                                              const float* __restrict__ bias, float* __restrict__ out,
                                              int M, int K,
                                              const float* __restrict__ x, const float* __restrict__ h2,
                                              const float* __restrict__ y2) {
  const int n0 = blockIdx.x * 256;
  const int m0 = blockIdx.y * 16;
  const int tid = threadIdx.x;
  const int tn = (tid & 63) * 4;
  const int tm = (tid >> 6) * 4;
  __shared__ float sA[16][16];
  __shared__ float sB[16][256];
  float acc[4][4] = {};
  for (int k0 = 0; k0 < K; k0 += 16) {
    __syncthreads();
    {
      int ml = tid & 15, kl = tid >> 4;
      float v = 0.f;
      if (m0 + ml < M && k0 + kl < K) v = A[(size_t)(m0 + ml) * K + k0 + kl];
      sA[kl][ml] = v;
    }
    for (int e = tid; e < 16 * 64; e += 256) {
      int kl = e >> 6, nn4 = e & 63;
      float4 v = make_float4(0.f, 0.f, 0.f, 0.f);
      if (k0 + kl < K) v = *reinterpret_cast<const float4*>(&B[(size_t)(k0 + kl) * HW + n0 + nn4 * 4]);
      reinterpret_cast<float4*>(&sB[kl][0])[nn4] = v;
    }
    __syncthreads();
#pragma unroll
    for (int k = 0; k < 16; k++) {
      float4 a4 = *reinterpret_cast<const float4*>(&sA[k][tm]);
      float4 b4 = *reinterpret_cast<const float4*>(&sB[k][tn]);
      acc[0][0] = fmaf(a4.x, b4.x, acc[0][0]); acc[0][1] = fmaf(a4.x, b4.y, acc[0][1]);
      acc[0][2] = fmaf(a4.x, b4.z, acc[0][2]); acc[0][3] = fmaf(a4.x, b4.w, acc[0][3]);
      acc[1][0] = fmaf(a4.y, b4.x, acc[1][0]); acc[1][1] = fmaf(a4.y, b4.y, acc[1][1]);
      acc[1][2] = fmaf(a4.y, b4.z, acc[1][2]); acc[1][3] = fmaf(a4.y, b4.w, acc[1][3]);
      acc[2][0] = fmaf(a4.z, b4.x, acc[2][0]); acc[2][1] = fmaf(a4.z, b4.y, acc[2][1]);
      acc[2][2] = fmaf(a4.z, b4.z, acc[2][2]); acc[2][3] = fmaf(a4.z, b4.w, acc[2][3]);
      acc[3][0] = fmaf(a4.w, b4.x, acc[3][0]); acc[3][1] = fmaf(a4.w, b4.y, acc[3][1]);
      acc[3][2] = fmaf(a4.w, b4.z, acc[3][2]); acc[3][3] = fmaf(a4.w, b4.w, acc[3][3]);
    }
  }
#pragma unroll
  for (int i = 0; i < 4; i++) {
    int m = m0 + tm + i;
    if (m >= M) continue;
    size_t base = (size_t)m * HW + n0 + tn;
    float bv = bias ? bias[m] : 0.f;
    float4 o;
    o.x = acc[i][0] + bv; o.y = acc[i][1] + bv; o.z = acc[i][2] + bv; o.w = acc[i][3] + bv;
    if (FUSE == 1) {
      float yv = y2[m];
      float4 xv = *reinterpret_cast<const float4*>(&x[base]);
      float4 hv = *reinterpret_cast<const float4*>(&h2[base]);
      o.x += 2.f * xv.x + hv.x * yv * xv.x;
      o.y += 2.f * xv.y + hv.y * yv * xv.y;
      o.z += 2.f * xv.z + hv.z * yv * xv.z;
      o.w += 2.f * xv.w + hv.w * yv * xv.w;
    }
    *reinterpret_cast<float4*>(&out[base]) = o;
  }
}

// ---------------- prep: qkv f32 [720][4096] -> qT/kT bf16 [8][4096][32], vP bf16 [8][32][4096]
__global__ __launch_bounds__(256) void prep_qkv(const float* __restrict__ qkvb,
                                                __hip_bfloat16* __restrict__ qT,
                                                __hip_bfloat16* __restrict__ kT,
                                                __hip_bfloat16* __restrict__ vP) {
  const int h = blockIdx.y, t0 = blockIdx.x * 256;
  const int tid = threadIdx.x;
  __shared__ float sT[30][258];
  const float qscale = 0.26340180f;  // 30^-1/2 * log2(e)
#pragma unroll
  for (int sect = 0; sect < 2; sect++) {
    __syncthreads();
    for (int e = tid; e < 30 * 256; e += 256) {
      int d = e >> 8, t = e & 255;
      sT[d][t] = qkvb[(size_t)(h * 90 + sect * 30 + d) * HW + t0 + t];
    }
    __syncthreads();
    float sc = (sect == 0) ? qscale : 1.f;
    __hip_bfloat16* dst = (sect == 0 ? qT : kT) + (size_t)h * HW * 32;
    for (int e = tid; e < 256 * 16; e += 256) {
      int t = e >> 4, d2 = e & 15;
      float lo = 0.f, hi = 0.f;
      if (d2 < 15) { lo = sT[2 * d2][t] * sc; hi = sT[2 * d2 + 1][t] * sc; }
      unsigned u;
      asm("v_cvt_pk_bf16_f32 %0, %1, %2" : "=v"(u) : "v"(lo), "v"(hi));
      reinterpret_cast<unsigned*>(dst)[(size_t)(t0 + t) * 16 + d2] = u;
    }
  }
  for (int e = tid; e < 32 * 128; e += 256) {
    int d = e >> 7, t2 = e & 127;
    float lo = 0.f, hi = 0.f;
    if (d < 30) {
      const float* src = qkvb + (size_t)(h * 90 + 60 + d) * HW + t0;
      lo = src[2 * t2];
      hi = src[2 * t2 + 1];
    }
    unsigned u;
    asm("v_cvt_pk_bf16_f32 %0, %1, %2" : "=v"(u) : "v"(lo), "v"(hi));
    reinterpret_cast<unsigned*>(vP)[((size_t)(h * 32 + d) * HW + t0) / 2 + t2] = u;
  }
}

// ---------------- MFMA flash attention (split-KV=2 partials) ----------------
__global__ __launch_bounds__(256) void flash_mfma(const __hip_bfloat16* __restrict__ qT,
                                                  const __hip_bfloat16* __restrict__ kT,
                                                  const __hip_bfloat16* __restrict__ vP,
                                                  float* __restrict__ pacc,
                                                  float* __restrict__ pm, float* __restrict__ pl) {
  const int h = blockIdx.y, sp = blockIdx.z;
  const int wid = threadIdx.x >> 6, lane = threadIdx.x & 63;
  const int l15 = lane & 15, lg = lane >> 4;
  const int qw = blockIdx.x * 64 + wid * 16;
  const __hip_bfloat16* qTh = qT + (size_t)h * HW * 32;
  const __hip_bfloat16* kTh = kT + (size_t)h * HW * 32;
  const __hip_bfloat16* vPh = vP + (size_t)h * 32 * HW;

  bf16x8 qa = *reinterpret_cast<const bf16x8*>(qTh + (size_t)(qw + l15) * 32 + lg * 8);

  f32x4 o0 = {0.f, 0.f, 0.f, 0.f}, o1 = {0.f, 0.f, 0.f, 0.f};
  float m[4] = {-1e30f, -1e30f, -1e30f, -1e30f};
  float lsum[4] = {0.f, 0.f, 0.f, 0.f};

  __shared__ ushort plds_all[4][64][20];
  ushort (*plds)[20] = plds_all[wid];

  const int srcl = (l15 >> 2) << 4;
  const int rr = l15 & 3;

  const int k_begin = sp * 2048;
  for (int k0 = k_begin; k0 < k_begin + 2048; k0 += 64) {
    f32x4 s[4];
#pragma unroll
    for (int t = 0; t < 4; t++) {
      bf16x8 kb = *reinterpret_cast<const bf16x8*>(kTh + (size_t)(k0 + t * 16 + l15) * 32 + lg * 8);
      f32x4 z = {0.f, 0.f, 0.f, 0.f};
      s[t] = __builtin_amdgcn_mfma_f32_16x16x32_bf16(qa, kb, z, 0, 0, 0);
    }
    float a[4];
#pragma unroll
    for (int r = 0; r < 4; r++) {
      float v = fmaxf(fmaxf(s[0][r], s[1][r]), fmaxf(s[2][r], s[3][r]));
      v = fmaxf(v, __shfl_xor(v, 1));
      v = fmaxf(v, __shfl_xor(v, 2));
      v = fmaxf(v, __shfl_xor(v, 4));
      v = fmaxf(v, __shfl_xor(v, 8));
      float mn = fmaxf(m[r], v);
      a[r] = exp2f(m[r] - mn);
      m[r] = mn;
      float rs = 0.f;
#pragma unroll
      for (int t = 0; t < 4; t++) {
        s[t][r] = exp2f(s[t][r] - mn);
        rs += s[t][r];
      }
      rs += __shfl_xor(rs, 1);
      rs += __shfl_xor(rs, 2);
      rs += __shfl_xor(rs, 4);
      rs += __shfl_xor(rs, 8);
      lsum[r] = lsum[r] * a[r] + rs;
    }
    float a0 = __shfl(a[0], srcl), a1 = __shfl(a[1], srcl);
    float a2 = __shfl(a[2], srcl), a3 = __shfl(a[3], srcl);
    float aq = rr == 0 ? a0 : (rr == 1 ? a1 : (rr == 2 ? a2 : a3));
    o0 *= aq;
    o1 *= aq;
#pragma unroll
    for (int t = 0; t < 4; t++) {
      unsigned u01, u23;
      asm("v_cvt_pk_bf16_f32 %0, %1, %2" : "=v"(u01) : "v"(s[t][0]), "v"(s[t][1]));
      asm("v_cvt_pk_bf16_f32 %0, %1, %2" : "=v"(u23) : "v"(s[t][2]), "v"(s[t][3]));
      *reinterpret_cast<uint2*>(&plds[t * 16 + l15][4 * lg]) = make_uint2(u01, u23);
    }
#pragma unroll
    for (int s2 = 0; s2 < 2; s2++) {
      union { ushort u[8]; bf16x8 v; } pb;
#pragma unroll
      for (int j = 0; j < 8; j++) pb.u[j] = plds[s2 * 32 + lg * 8 + j][l15];
      bf16x8 va0 = *reinterpret_cast<const bf16x8*>(vPh + (size_t)l15 * HW + k0 + s2 * 32 + lg * 8);
      bf16x8 va1 = *reinterpret_cast<const bf16x8*>(vPh + (size_t)(16 + l15) * HW + k0 + s2 * 32 + lg * 8);
      o0 = __builtin_amdgcn_mfma_f32_16x16x32_bf16(va0, pb.v, o0, 0, 0, 0);
      o1 = __builtin_amdgcn_mfma_f32_16x16x32_bf16(va1, pb.v, o1, 0, 0, 0);
    }
  }
  const int sh = sp * 8 + h;
  if (l15 == 0) {
#pragma unroll
    for (int r = 0; r < 4; r++) {
      pm[(size_t)sh * HW + qw + 4 * lg + r] = m[r];
      pl[(size_t)sh * HW + qw + 4 * lg + r] = lsum[r];
    }
  }
  float* pbase = pacc + (size_t)sh * 30 * HW;
#pragma unroll
  for (int r = 0; r < 4; r++) {
    int d = 4 * lg + r;
    if (d < 30) pbase[(size_t)d * HW + qw + l15] = o0[r];
    if (d + 16 < 30) pbase[(size_t)(d + 16) * HW + qw + l15] = o1[r];
  }
}

// ---------------- flash merge (exp2 domain, 2 splits) ----------------
__global__ __launch_bounds__(256) void flash_merge(const float* __restrict__ pacc,
                                                   const float* __restrict__ pm, const float* __restrict__ pl,
                                                   float* __restrict__ hs) {
  int idx = blockIdx.x * 256 + threadIdx.x;
  if (idx >= CCH * HW) return;
  int c = idx >> 12;
  int t = idx & 4095;
  int hh = c / 30;
  int d = c % 30;
  float pmv[2];
  float mx = -1e30f;
#pragma unroll
  for (int sp = 0; sp < 2; sp++) {
    pmv[sp] = pm[(size_t)(sp * 8 + hh) * HW + t];
    mx = fmaxf(mx, pmv[sp]);
  }
  float den = 0.f, num = 0.f;
#pragma unroll
  for (int sp = 0; sp < 2; sp++) {
    float wgt = exp2f(pmv[sp] - mx);
    den = fmaf(pl[(size_t)(sp * 8 + hh) * HW + t], wgt, den);
    num = fmaf(pacc[((size_t)(sp * 8 + hh) * 30 + d) * HW + t], wgt, num);
  }
  hs[idx] = num / den;
}

// ---------------- launch ----------------
extern "C" void kernel_launch(void* const* d_in, const int* in_sizes, int n_in,
                              void* d_out, int out_size, void* d_ws, size_t ws_size,
                              hipStream_t stream) {
  const float* x        = (const float*)d_in[0];
  const float* ca_gn1_g = (const float*)d_in[1];
  const float* ca_gn1_b = (const float*)d_in[2];
  const float* ca_c1_w  = (const float*)d_in[3];
  const float* ca_c1_b  = (const float*)d_in[4];
  const float* ca_gn2_g = (const float*)d_in[5];
  const float* ca_gn2_b = (const float*)d_in[6];
  const float* ca_c2_w  = (const float*)d_in[7];
  const float* ca_c2_b  = (const float*)d_in[8];
  const float* se1_w    = (const float*)d_in[9];
  const float* se1_b    = (const float*)d_in[10];
  const float* se2_w    = (const float*)d_in[11];
  const float* se2_b    = (const float*)d_in[12];
  const float* sa_gn_g  = (const float*)d_in[13];
  const float* sa_gn_b  = (const float*)d_in[14];
  const float* qkv_w    = (const float*)d_in[15];
  const float* proj_w   = (const float*)d_in[16];
  const float* proj_b   = (const float*)d_in[17];
  const float* res_gn_g = (const float*)d_in[18];
  const float* res_gn_b = (const float*)d_in[19];
  const float* res_w    = (const float*)d_in[20];
  const float* res_b    = (const float*)d_in[21];
  float* out = (float*)d_out;
  float* ws = (float*)d_ws;

  // workspace layout (floats); high-water unchanged at 9.93M fl = 39.7 MB
  float* h1   = ws + 0;         // 983040   (reused as hs)
  float* xn   = ws + 983040;    // 983040   (reused as t)
  float* c1   = ws + 1966080;   // 245760   (reused as pm/pl during flash)
  float* c1n  = ws + 2211840;   // 245760
  float* h2   = ws + 2457600;   // 983040
  float* qkvb = ws + 3440640;   // 2949120  (reused as tn)
  float* pacc = ws + 6389760;   // 1966080  (transients sublet below)
  __hip_bfloat16* qTb = (__hip_bfloat16*)(ws + 8355840);
  __hip_bfloat16* kTb = (__hip_bfloat16*)(ws + 8880128);
  __hip_bfloat16* vPb = (__hip_bfloat16*)(ws + 9404416);
  float* S    = ws + 9928704;
  float* csx = S + 0,   *cqx = S + 240;
  float* cs2 = S + 512, *cq2 = S + 576;
  float* csh = S + 704, *cqh = S + 944;
  float* y2g = S + 1184;
  float* csr = S + 1424, *cqr = S + 1664;
  float* pm = ws + 1966080;           // 2*8*4096 in dead c1 region
  float* pl = ws + 1966080 + 65536;
  float* hs = h1;
  float* t  = xn;
  float* tn = qkvb;

  // pacc region sublets (time-disjoint with flash partials):
  // phase A (pre-flash): h1T, c1nT, wB1, wB2
  __hip_bfloat16* h1T  = (__hip_bfloat16*)(pacc);            // 4097*256 bf16 = 524416 fl
  __hip_bfloat16* c1nT = (__hip_bfloat16*)(pacc + 524416);   // 4097*64  bf16 = 131104 fl
  __hip_bfloat16* wB1  = (__hip_bfloat16*)(pacc + 655520);   // 9*64*256 bf16 = 73728 fl
  __hip_bfloat16* wB2  = (__hip_bfloat16*)(pacc + 729248);   // 9*256*64 bf16 = 73728 fl  (end 802976)
  // phase B (post-merge): wB3, tnT
  __hip_bfloat16* wB3  = (__hip_bfloat16*)(pacc);            // 9*256*256 bf16 = 294912 fl
  __hip_bfloat16* tnT  = (__hip_bfloat16*)(pacc + 294912);   // 524416 fl (end 819328)

  // --- CAB branch ---
  chan_stats<<<240, 256, 0, stream>>>(x, csx, cqx);
  apply_x<<<960, 256, 0, stream>>>(x, csx, cqx, ca_gn1_g, ca_gn1_b, sa_gn_g, sa_gn_b, h1, xn);
  tp_bf16<256><<<dim3(65, 4), 256, 0, stream>>>(h1, h1T, 240);
  repack_w<<<288, 256, 0, stream>>>(ca_c1_w, wB1, 60, 240, 64, 256);
  conv_mfma<256, 0><<<dim3(64, 2), 256, 0, stream>>>(h1T, wB1, ca_c1_b, c1, 60, 64, nullptr);
  chan_stats<<<60, 256, 0, stream>>>(c1, cs2, cq2);
  apply_gn_silu<<<240, 256, 0, stream>>>(c1, cs2, cq2, ca_gn2_g, ca_gn2_b, c1n, 60, 15);
  tp_bf16<64><<<dim3(65, 1), 256, 0, stream>>>(c1n, c1nT, 60);
  repack_w<<<288, 256, 0, stream>>>(ca_c2_w, wB2, 240, 60, 256, 64);
  conv_mfma<64, 0><<<dim3(64, 8), 256, 0, stream>>>(c1nT, wB2, ca_c2_b, h2, 240, 256, nullptr);
  chan_stats<<<240, 256, 0, stream>>>(h2, csh, cqh);
  se_kernel<<<1, 256, 0, stream>>>(csh, se1_w, se1_b, se2_w, se2_b, y2g);
  // --- attention branch ---
  gemm16<0><<<dim3(16, 45), 256, 0, stream>>>(qkv_w, xn, nullptr, qkvb, 720, 240,
                                              nullptr, nullptr, nullptr);
  prep_qkv<<<dim3(16, 8), 256, 0, stream>>>(qkvb, qTb, kTb, vPb);
  flash_mfma<<<dim3(64, 8, 2), 256, 0, stream>>>(qTb, kTb, vPb, pacc, pm, pl);
  flash_merge<<<3840, 256, 0, stream>>>(pacc, pm, pl, hs);
  // --- residual fusion ---
  repack_w<<<1152, 256, 0, stream>>>(res_w, wB3, 240, 240, 256, 256);
  gemm16<1><<<dim3(16, 15), 256, 0, stream>>>(proj_w, hs, proj_b, t, 240, 240, x, h2, y2g);
  chan_stats<<<240, 256, 0, stream>>>(t, csr, cqr);
  apply_gn_silu<<<960, 256, 0, stream>>>(t, csr, cqr, res_gn_g, res_gn_b, tn, 240, 60);
  tp_bf16<256><<<dim3(65, 4), 256, 0, stream>>>(tn, tnT, 240);
  conv_mfma<256, 1><<<dim3(64, 8), 256, 0, stream>>>(tnT, wB3, res_b, out, 240, 256, x);
}